// Round 7
// baseline (1456.700 us; speedup 1.0000x reference)
//
#include <hip/hip_runtime.h>
#include <hip/hip_bf16.h>

typedef unsigned short u16;
typedef unsigned int u32;
typedef __bf16 bf16x8 __attribute__((ext_vector_type(8)));
typedef float f32x4 __attribute__((ext_vector_type(4)));

#define DEV static __device__ __forceinline__
#define GPTR(p) (const __attribute__((address_space(1))) u32*)(p)
#define LPTR(p) (__attribute__((address_space(3))) u32*)(p)

DEV float bf2f(u16 u) { return __uint_as_float((u32)u << 16); }
DEV u16 f2bf(float f) {
  u32 x = __float_as_uint(f);
  x += 0x7fffu + ((x >> 16) & 1u);
  return (u16)(x >> 16);
}
DEV float gelu_f(float x) { return 0.5f * x * (1.0f + erff(x * 0.70710678118654752440f)); }

// ---------------------------------------------------------------- convert f32 -> bf16
__global__ void cvt_k(const float* __restrict__ in, u16* __restrict__ out, int n4) {
  int i = blockIdx.x * 256 + threadIdx.x;
  if (i < n4) {
    float4 v = ((const float4*)in)[i];
    ushort4 o;
    o.x = f2bf(v.x); o.y = f2bf(v.y); o.z = f2bf(v.z); o.w = f2bf(v.w);
    ((ushort4*)out)[i] = o;
  }
}

// transpose h0_w1 (64,1024) -> (1024,64) f32
__global__ void w1t_k(const float* __restrict__ w1, float* __restrict__ w1t) {
  int i = blockIdx.x * 256 + threadIdx.x;
  if (i < 64 * 1024) {
    int o = i >> 10, c = i & 1023;
    w1t[c * 64 + o] = w1[i];
  }
}

// ---------------------------------------------------------------- LayerNorm (row per block)
// OUTM: 0 = bf16 out, 1 = f32 out
template<int DIM, int OUTM>
__global__ __launch_bounds__(256) void ln_k(const float* __restrict__ in,
                                            const float* __restrict__ g,
                                            const float* __restrict__ b,
                                            void* __restrict__ outp) {
  constexpr int NV = DIM / 1024;  // float4 per thread
  const int row = blockIdx.x, tid = threadIdx.x;
  const float* x = in + (size_t)row * DIM;
  float4 v[NV];
  float s = 0.f, s2 = 0.f;
#pragma unroll
  for (int i = 0; i < NV; ++i) {
    v[i] = ((const float4*)x)[tid + i * 256];
    s += v[i].x + v[i].y + v[i].z + v[i].w;
    s2 += v[i].x * v[i].x + v[i].y * v[i].y + v[i].z * v[i].z + v[i].w * v[i].w;
  }
  __shared__ float red[8];
#pragma unroll
  for (int off = 32; off; off >>= 1) { s += __shfl_down(s, off); s2 += __shfl_down(s2, off); }
  if ((tid & 63) == 0) { red[(tid >> 6) * 2] = s; red[(tid >> 6) * 2 + 1] = s2; }
  __syncthreads();
  s = red[0] + red[2] + red[4] + red[6];
  s2 = red[1] + red[3] + red[5] + red[7];
  const float mean = s / DIM;
  const float rstd = rsqrtf(s2 / DIM - mean * mean + 1e-5f);
#pragma unroll
  for (int i = 0; i < NV; ++i) {
    const int c4 = tid + i * 256;
    float4 gv = ((const float4*)g)[c4];
    float4 bv = ((const float4*)b)[c4];
    float o0 = (v[i].x - mean) * rstd * gv.x + bv.x;
    float o1 = (v[i].y - mean) * rstd * gv.y + bv.y;
    float o2 = (v[i].z - mean) * rstd * gv.z + bv.z;
    float o3 = (v[i].w - mean) * rstd * gv.w + bv.w;
    if (OUTM == 0) {
      ushort4 u4;
      u4.x = f2bf(o0); u4.y = f2bf(o1); u4.z = f2bf(o2); u4.w = f2bf(o3);
      ((ushort4*)outp)[(size_t)row * (DIM / 4) + c4] = u4;
    } else {
      ((float4*)outp)[(size_t)row * (DIM / 4) + c4] = make_float4(o0, o1, o2, o3);
    }
  }
}

// ---------------------------------------------------------------- bf16 NT GEMM + epilogues
// C[m,n] = sum_k A[m,k] * B[n,k] + bias[n]
// Deep pipeline, RACE-FIXED: per tile t the order is
//   s_waitcnt vmcnt(counted)  -- this wave's tile-t DMA landed
//   s_barrier                 -- ALL waves' tile-t DMA landed; all reads of
//                                slot (t+2)%3 (done in tile t-1) completed
//   { ds_read slot t%3 | stage tile t+2 -> slot (t+2)%3 | MFMA } phases
// Counted vmcnt never drains to 0 mid-loop: tile t+1's loads stay in flight
// across the barrier (~2 tiles of cover > HBM latency). One barrier per tile.
// 512 threads (8 waves), BM=128, BN in {128,64}, BK=64, ring-of-3 LDS.
// Verified-zero-conflict both-sides XOR swizzle; bijective XCD swizzle.
// EPI: 0 = gelu -> f32, 1 = -> bf16, 2 = residual add -> f32 (in place), 3 = relu -> bf16
template<int EPI, int BN>
__global__ __launch_bounds__(512, 4) void gemm_bt(const u16* __restrict__ A,
                                                  const u16* __restrict__ B,
                                                  const float* __restrict__ bias,
                                                  float* __restrict__ Cf,
                                                  u16* __restrict__ Cb,
                                                  int N, int K, int nx) {
  constexpr int MR = (BN == 128) ? 4 : 2;
  constexpr int ASLOT = 128 * 64;  // elems per A slot
  constexpr int BSLOT = BN * 64;
  __shared__ u16 As[3][ASLOT];
  __shared__ u16 Bs[3][BSLOT];
  const int tid = threadIdx.x;
  const int nwg = gridDim.x, bid = blockIdx.x;
  const int swz = (bid & 7) * (nwg >> 3) + (bid >> 3);  // nwg % 8 == 0 always here
  const int by = swz / nx, bx = swz - by * nx;
  const int brow = by * 128, bcol = bx * BN;
  const int lane = tid & 63, w = tid >> 6;
  const int wr = (BN == 128) ? ((w >> 2) * 64) : ((w >> 1) * 32);
  const int wc = (BN == 128) ? ((w & 3) * 32) : ((w & 1) * 32);
  const int fr = lane & 15, fg = lane >> 4;
  const int swb = (fr & 7) << 4;                  // read-side XOR (bytes in 128B row)
  const int srow = tid >> 3;                      // 0..63 staging row within a 64-row half
  const int scol = ((tid & 7) ^ (srow & 7)) * 8;  // inverse-swizzled source col (elems)

  const u16* Ag = A + (size_t)(brow + srow) * K + scol;
  const u16* Bg = B + (size_t)(bcol + srow) * K + scol;

  f32x4 acc[MR][2];
  const f32x4 z = {0.f, 0.f, 0.f, 0.f};
#pragma unroll
  for (int m = 0; m < MR; ++m) { acc[m][0] = z; acc[m][1] = z; }

  auto stageA = [&](int kt, int s, int h) {
    __builtin_amdgcn_global_load_lds(GPTR(Ag + (size_t)h * 64 * K + (kt << 6)),
                                     LPTR(&As[s][h * 4096 + tid * 8]), 16, 0, 0);
  };
  auto stageB = [&](int kt, int s, int h) {
    __builtin_amdgcn_global_load_lds(GPTR(Bg + (size_t)h * 64 * K + (kt << 6)),
                                     LPTR(&Bs[s][h * 4096 + tid * 8]), 16, 0, 0);
  };
  auto rdA = [&](int s, int m, int ks) -> bf16x8 {
    const int rr = wr + m * 16 + fr;
    return *(const bf16x8*)((const char*)&As[s][0] + rr * 128 + ((ks * 64 + fg * 16) ^ swb));
  };
  auto rdB = [&](int s, int n, int ks) -> bf16x8 {
    const int rb = wc + n * 16 + fr;
    return *(const bf16x8*)((const char*)&Bs[s][0] + rb * 128 + ((ks * 64 + fg * 16) ^ swb));
  };

  const int nkt = K >> 6;
  // prologue: tiles 0,1 -> slots 0,1
#pragma unroll
  for (int t = 0; t < 2; ++t) {
    stageA(t, t, 0); stageA(t, t, 1);
    stageB(t, t, 0);
    if (BN == 128) stageB(t, t, 1);
  }
  int s0 = 0, s2 = 2;

  for (int t = 0; t < nkt; ++t) {
    const bool pre = (t + 2 < nkt);
    // counted wait: only tile t's loads must have landed (this wave's part)
    if (t == nkt - 1) asm volatile("s_waitcnt vmcnt(0)" ::: "memory");
    else if constexpr (BN == 128) asm volatile("s_waitcnt vmcnt(4)" ::: "memory");
    else asm volatile("s_waitcnt vmcnt(3)" ::: "memory");
    // join: after this, ALL waves' tile-t DMA landed, and every wave finished
    // its tile-(t-1) reads of slot s2 -> safe to read s0 and stage into s2.
    __builtin_amdgcn_s_barrier();
    __builtin_amdgcn_sched_barrier(0);

    if constexpr (BN == 128) {
#pragma unroll
      for (int ks = 0; ks < 2; ++ks) {  // two phases per tile
        bf16x8 af[4], bf2r[2];
#pragma unroll
        for (int m = 0; m < 4; ++m) af[m] = rdA(s0, m, ks);
#pragma unroll
        for (int n = 0; n < 2; ++n) bf2r[n] = rdB(s0, n, ks);
        if (pre) { stageA(t + 2, s2, ks); stageB(t + 2, s2, ks); }
        __builtin_amdgcn_sched_barrier(0);
        __builtin_amdgcn_s_setprio(1);
#pragma unroll
        for (int m = 0; m < 4; ++m)
#pragma unroll
          for (int n = 0; n < 2; ++n)
            acc[m][n] = __builtin_amdgcn_mfma_f32_16x16x32_bf16(af[m], bf2r[n], acc[m][n], 0, 0, 0);
        __builtin_amdgcn_s_setprio(0);
        __builtin_amdgcn_sched_barrier(0);
      }
    } else {
      bf16x8 af[2][2], bf2r[2][2];
#pragma unroll
      for (int ks = 0; ks < 2; ++ks) {
#pragma unroll
        for (int m = 0; m < 2; ++m) af[m][ks] = rdA(s0, m, ks);
#pragma unroll
        for (int n = 0; n < 2; ++n) bf2r[n][ks] = rdB(s0, n, ks);
      }
      if (pre) { stageA(t + 2, s2, 0); stageA(t + 2, s2, 1); stageB(t + 2, s2, 0); }
      __builtin_amdgcn_sched_barrier(0);
      __builtin_amdgcn_s_setprio(1);
#pragma unroll
      for (int ks = 0; ks < 2; ++ks)
#pragma unroll
        for (int m = 0; m < 2; ++m)
#pragma unroll
          for (int n = 0; n < 2; ++n)
            acc[m][n] = __builtin_amdgcn_mfma_f32_16x16x32_bf16(af[m][ks], bf2r[n][ks], acc[m][n], 0, 0, 0);
      __builtin_amdgcn_s_setprio(0);
      __builtin_amdgcn_sched_barrier(0);
    }
    s0 = (s0 == 2) ? 0 : s0 + 1;
    s2 = (s2 == 2) ? 0 : s2 + 1;
  }

#pragma unroll
  for (int n = 0; n < 2; ++n) {
    const int col = bcol + wc + n * 16 + fr;
    const float bv = bias[col];
#pragma unroll
    for (int m = 0; m < MR; ++m) {
      const int row0 = brow + wr + m * 16 + fg * 4;
#pragma unroll
      for (int j = 0; j < 4; ++j) {
        float v = acc[m][n][j] + bv;
        const size_t idx = (size_t)(row0 + j) * N + col;
        if (EPI == 0) Cf[idx] = gelu_f(v);
        else if (EPI == 1) Cb[idx] = f2bf(v);
        else if (EPI == 2) Cf[idx] = Cf[idx] + v;
        else Cb[idx] = f2bf(fmaxf(v, 0.f));
      }
    }
  }
}

// ---------------------------------------------------------------- attention: one block per (b,h)
__global__ __launch_bounds__(256) void attn_k(const u16* __restrict__ qkv, u16* __restrict__ o) {
  constexpr int LDQ = 136;  // padded stride (bf16 elems)
  __shared__ u16 Q[36 * LDQ], Kk[36 * LDQ], V[36 * LDQ];
  __shared__ float S[36][38];
  const int tid = threadIdx.x;
  const int b = blockIdx.x >> 3, h = blockIdx.x & 7;
  const size_t base = (size_t)b * 36 * 3072 + h * 128;
  for (int i = tid; i < 36 * 16; i += 256) {
    const int r = i >> 4, c = (i & 15) << 3;
    const size_t src = base + (size_t)r * 3072 + c;
    *(uint4*)&Q[r * LDQ + c] = *(const uint4*)&qkv[src];
    *(uint4*)&Kk[r * LDQ + c] = *(const uint4*)&qkv[src + 1024];
    *(uint4*)&V[r * LDQ + c] = *(const uint4*)&qkv[src + 2048];
  }
  __syncthreads();
  for (int i = tid; i < 36 * 36; i += 256) {
    const int r = i / 36, c = i - r * 36;
    float s = 0.f;
    for (int d = 0; d < 128; ++d) s += bf2f(Q[r * LDQ + d]) * bf2f(Kk[c * LDQ + d]);
    S[r][c] = s * 0.08838834764831845f;
  }
  __syncthreads();
  if (tid < 36) {
    float mx = -1e30f;
    for (int c = 0; c < 36; ++c) mx = fmaxf(mx, S[tid][c]);
    float sum = 0.f;
    for (int c = 0; c < 36; ++c) { float e = expf(S[tid][c] - mx); S[tid][c] = e; sum += e; }
    const float inv = 1.f / sum;
    for (int c = 0; c < 36; ++c) S[tid][c] *= inv;
  }
  __syncthreads();
  for (int i = tid; i < 36 * 16; i += 256) {
    const int r = i >> 4, d0 = (i & 15) << 3;
    float s[8] = {0.f, 0.f, 0.f, 0.f, 0.f, 0.f, 0.f, 0.f};
    for (int j = 0; j < 36; ++j) {
      const float p = S[r][j];
#pragma unroll
      for (int e = 0; e < 8; ++e) s[e] += p * bf2f(V[j * LDQ + d0 + e]);
    }
    uint4 pk;
    pk.x = (u32)f2bf(s[0]) | ((u32)f2bf(s[1]) << 16);
    pk.y = (u32)f2bf(s[2]) | ((u32)f2bf(s[3]) << 16);
    pk.z = (u32)f2bf(s[4]) | ((u32)f2bf(s[5]) << 16);
    pk.w = (u32)f2bf(s[6]) | ((u32)f2bf(s[7]) << 16);
    *(uint4*)&o[(size_t)(b * 36 + r) * 1024 + h * 128 + d0] = pk;
  }
}

// ---------------------------------------------------------------- attention-map head (per token)
__global__ __launch_bounds__(256) void h0_k(const float* __restrict__ xr,
                                            const float* __restrict__ w1t,
                                            const float* __restrict__ b1,
                                            const float* __restrict__ w2,
                                            const float* __restrict__ b2v,
                                            float* __restrict__ full) {
  __shared__ float xs[1024];
  __shared__ float hp[4][64];
  const int token = blockIdx.x, tid = threadIdx.x;
  ((float4*)xs)[tid] = ((const float4*)(xr + (size_t)token * 1024))[tid];
  __syncthreads();
  const int w = tid >> 6, lane = tid & 63;
  float s = 0.f;
  const int c0 = w * 256;
  for (int c = c0; c < c0 + 256; ++c) s += xs[c] * w1t[c * 64 + lane];
  hp[w][lane] = s;
  __syncthreads();
  if (tid < 64) {
    float h = hp[0][tid] + hp[1][tid] + hp[2][tid] + hp[3][tid] + b1[tid];
    h = gelu_f(h);
    float v = h * w2[tid];
#pragma unroll
    for (int off = 32; off; off >>= 1) v += __shfl_down(v, off);
    if (tid == 0) full[token] = v + b2v[0];
  }
}

__global__ void am2_k(const float* __restrict__ full, const float* __restrict__ temp,
                      float* __restrict__ out) {
  const int i = blockIdx.x * 256 + threadIdx.x;
  if (i < 128 * 36 * 35) {
    const int j = i % 35;
    const int t = i / 35;
    const int p = t % 36;
    const int b = t / 36;
    const int col = j + (j >= p ? 1 : 0);
    const float v = full[b * 36 + col] / temp[0];
    out[i] = 1.f / (1.f + expf(-v));
  }
}

// ---------------------------------------------------------------- launch
extern "C" void kernel_launch(void* const* d_in, const int* in_sizes, int n_in,
                              void* d_out, int out_size, void* d_ws, size_t ws_size,
                              hipStream_t stream) {
  const float* x     = (const float*)d_in[0];
  const float* ln0_g = (const float*)d_in[1];
  const float* ln0_b = (const float*)d_in[2];
  const float* Wred  = (const float*)d_in[3];
  const float* bred  = (const float*)d_in[4];
  const float* h0_w1 = (const float*)d_in[5];
  const float* h0_b1 = (const float*)d_in[6];
  const float* h0_w2 = (const float*)d_in[7];
  const float* h0_b2 = (const float*)d_in[8];
  const float* temp  = (const float*)d_in[9];
  const float* Wqkv  = (const float*)d_in[10];
  const float* bqkv  = (const float*)d_in[11];
  const float* Wo    = (const float*)d_in[12];
  const float* bo    = (const float*)d_in[13];
  const float* ln1_g = (const float*)d_in[14];
  const float* ln1_b = (const float*)d_in[15];
  const float* W1    = (const float*)d_in[16];
  const float* b1    = (const float*)d_in[17];
  const float* W2    = (const float*)d_in[18];
  const float* b2    = (const float*)d_in[19];
  const float* ln2_g = (const float*)d_in[20];
  const float* ln2_b = (const float*)d_in[21];
  const float* lnf_g = (const float*)d_in[22];
  const float* lnf_b = (const float*)d_in[23];

  char* ws = (char*)d_ws;
  size_t off = 0;
  auto alloc = [&](size_t bytes) -> void* {
    void* p = ws + off;
    off += (bytes + 255) & ~(size_t)255;
    return p;
  };
  u16* WredB  = (u16*)alloc((size_t)1024 * 3072 * 2);
  u16* WqkvB  = (u16*)alloc((size_t)6 * 3072 * 1024 * 2);
  u16* WoB    = (u16*)alloc((size_t)6 * 1024 * 1024 * 2);
  u16* W1B    = (u16*)alloc((size_t)6 * 2048 * 1024 * 2);
  u16* W2B    = (u16*)alloc((size_t)6 * 1024 * 2048 * 2);
  float* w1t  = (float*)alloc((size_t)1024 * 64 * 4);
  float* yb   = (float*)alloc((size_t)4608 * 1024 * 4);
  u16* big    = (u16*)alloc((size_t)4608 * 3072 * 2);   // xn / qkv / f
  u16* nbuf   = (u16*)alloc((size_t)4608 * 1024 * 2);   // ynorm / o
  float* fullb = (float*)alloc((size_t)4608 * 4);

  auto cvt = [&](const float* src, u16* dst, size_t n) {
    int n4 = (int)(n / 4);
    cvt_k<<<(n4 + 255) / 256, 256, 0, stream>>>(src, dst, n4);
  };
  cvt(Wred, WredB, (size_t)1024 * 3072);
  cvt(Wqkv, WqkvB, (size_t)6 * 3072 * 1024);
  cvt(Wo,   WoB,   (size_t)6 * 1024 * 1024);
  cvt(W1,   W1B,   (size_t)6 * 2048 * 1024);
  cvt(W2,   W2B,   (size_t)6 * 1024 * 2048);
  w1t_k<<<64 * 1024 / 256, 256, 0, stream>>>(h0_w1, w1t);

  // dim reduce: xr = gelu(LN0(x) @ Wred^T + bred) -> yb (f32)
  ln_k<3072, 0><<<4608, 256, 0, stream>>>(x, ln0_g, ln0_b, big);
  gemm_bt<0, 64><<<16 * 36, 512, 0, stream>>>(big, WredB, bred, yb, nullptr, 1024, 3072, 16);
  // attention maps head
  h0_k<<<4608, 256, 0, stream>>>(yb, w1t, h0_b1, h0_w2, h0_b2, fullb);
  am2_k<<<(128 * 36 * 35 + 255) / 256, 256, 0, stream>>>(fullb, temp,
                                                         (float*)d_out + 4608 * 1024);

  for (int l = 0; l < 6; ++l) {
    ln_k<1024, 0><<<4608, 256, 0, stream>>>(yb, ln1_g + l * 1024, ln1_b + l * 1024, nbuf);
    gemm_bt<1, 128><<<24 * 36, 512, 0, stream>>>(nbuf, WqkvB + (size_t)l * 3072 * 1024,
                                                 bqkv + l * 3072, nullptr, big, 3072, 1024, 24);
    attn_k<<<128 * 8, 256, 0, stream>>>(big, nbuf);
    gemm_bt<2, 64><<<16 * 36, 512, 0, stream>>>(nbuf, WoB + (size_t)l * 1024 * 1024,
                                                bo + l * 1024, yb, nullptr, 1024, 1024, 16);
    ln_k<1024, 0><<<4608, 256, 0, stream>>>(yb, ln2_g + l * 1024, ln2_b + l * 1024, nbuf);
    gemm_bt<3, 128><<<16 * 36, 512, 0, stream>>>(nbuf, W1B + (size_t)l * 2048 * 1024,
                                                 b1 + l * 2048, nullptr, big, 2048, 1024, 16);
    gemm_bt<2, 64><<<16 * 36, 512, 0, stream>>>(big, W2B + (size_t)l * 1024 * 2048,
                                                b2 + l * 1024, yb, nullptr, 1024, 2048, 16);
  }
  ln_k<1024, 1><<<4608, 256, 0, stream>>>(yb, lnf_g, lnf_b, d_out);
}

// Round 8
// 1221.242 us; speedup vs baseline: 1.1928x; 1.1928x over previous
//
#include <hip/hip_runtime.h>
#include <hip/hip_bf16.h>

typedef unsigned short u16;
typedef unsigned int u32;
typedef __bf16 bf16x8 __attribute__((ext_vector_type(8)));
typedef float f32x4 __attribute__((ext_vector_type(4)));

#define DEV static __device__ __forceinline__
#define GPTR(p) (const __attribute__((address_space(1))) u32*)(p)
#define LPTR(p) (__attribute__((address_space(3))) u32*)(p)

DEV float bf2f(u16 u) { return __uint_as_float((u32)u << 16); }
DEV u16 f2bf(float f) {
  u32 x = __float_as_uint(f);
  x += 0x7fffu + ((x >> 16) & 1u);
  return (u16)(x >> 16);
}
DEV float gelu_f(float x) { return 0.5f * x * (1.0f + erff(x * 0.70710678118654752440f)); }

// ---------------------------------------------------------------- convert f32 -> bf16
__global__ void cvt_k(const float* __restrict__ in, u16* __restrict__ out, int n4) {
  int i = blockIdx.x * 256 + threadIdx.x;
  if (i < n4) {
    float4 v = ((const float4*)in)[i];
    ushort4 o;
    o.x = f2bf(v.x); o.y = f2bf(v.y); o.z = f2bf(v.z); o.w = f2bf(v.w);
    ((ushort4*)out)[i] = o;
  }
}

// transpose h0_w1 (64,1024) -> (1024,64) f32
__global__ void w1t_k(const float* __restrict__ w1, float* __restrict__ w1t) {
  int i = blockIdx.x * 256 + threadIdx.x;
  if (i < 64 * 1024) {
    int o = i >> 10, c = i & 1023;
    w1t[c * 64 + o] = w1[i];
  }
}

// ---------------------------------------------------------------- LayerNorm (row per block)
// INBF: 0 = f32 input, 1 = bf16 input. OUTM: 0 = bf16 out, 1 = f32 out.
template<int DIM, int OUTM, int INBF>
__global__ __launch_bounds__(256) void ln_k(const void* __restrict__ inp,
                                            const float* __restrict__ g,
                                            const float* __restrict__ b,
                                            void* __restrict__ outp) {
  constexpr int NV = DIM / 1024;  // 4-elem groups per thread
  const int row = blockIdx.x, tid = threadIdx.x;
  float4 v[NV];
  float s = 0.f, s2 = 0.f;
#pragma unroll
  for (int i = 0; i < NV; ++i) {
    if (INBF == 0) {
      v[i] = ((const float4*)inp)[(size_t)row * (DIM / 4) + tid + i * 256];
    } else {
      ushort4 u = ((const ushort4*)inp)[(size_t)row * (DIM / 4) + tid + i * 256];
      v[i] = make_float4(bf2f(u.x), bf2f(u.y), bf2f(u.z), bf2f(u.w));
    }
    s += v[i].x + v[i].y + v[i].z + v[i].w;
    s2 += v[i].x * v[i].x + v[i].y * v[i].y + v[i].z * v[i].z + v[i].w * v[i].w;
  }
  __shared__ float red[8];
#pragma unroll
  for (int off = 32; off; off >>= 1) { s += __shfl_down(s, off); s2 += __shfl_down(s2, off); }
  if ((tid & 63) == 0) { red[(tid >> 6) * 2] = s; red[(tid >> 6) * 2 + 1] = s2; }
  __syncthreads();
  s = red[0] + red[2] + red[4] + red[6];
  s2 = red[1] + red[3] + red[5] + red[7];
  const float mean = s / DIM;
  const float rstd = rsqrtf(s2 / DIM - mean * mean + 1e-5f);
#pragma unroll
  for (int i = 0; i < NV; ++i) {
    const int c4 = tid + i * 256;
    float4 gv = ((const float4*)g)[c4];
    float4 bv = ((const float4*)b)[c4];
    float o0 = (v[i].x - mean) * rstd * gv.x + bv.x;
    float o1 = (v[i].y - mean) * rstd * gv.y + bv.y;
    float o2 = (v[i].z - mean) * rstd * gv.z + bv.z;
    float o3 = (v[i].w - mean) * rstd * gv.w + bv.w;
    if (OUTM == 0) {
      ushort4 u4;
      u4.x = f2bf(o0); u4.y = f2bf(o1); u4.z = f2bf(o2); u4.w = f2bf(o3);
      ((ushort4*)outp)[(size_t)row * (DIM / 4) + c4] = u4;
    } else {
      ((float4*)outp)[(size_t)row * (DIM / 4) + c4] = make_float4(o0, o1, o2, o3);
    }
  }
}

// ---------------------------------------------------------------- bf16 NT GEMM + epilogues
// C[m,n] = sum_k A[m,k] * B[n,k] + bias[n]    (r3-proven structure)
// 512 threads (8 waves), BM=128, BN in {128,64}, BK=64.
// Double-buffered LDS, ONE raw s_barrier per K-step with per-wave vmcnt(0)
// (stage(t+1) issued a full tile before its consume -> latency covered).
// global_load_lds width-16, both-sides XOR swizzle (verified: 0 conflicts).
// EPI (all bf16 out): 0 = gelu, 1 = plain, 2 = residual add in-place, 3 = relu
template<int EPI, int BN>
__global__ __launch_bounds__(512, 4) void gemm_bt(const u16* __restrict__ A,
                                                  const u16* __restrict__ B,
                                                  const float* __restrict__ bias,
                                                  u16* __restrict__ Cb,
                                                  int N, int K, int nx) {
  constexpr int WC = BN / 32;               // waves along N
  constexpr int MR = (128 * WC / 8) / 16;   // 16-row frags per wave along M
  __shared__ u16 As[2][128 * 64];
  __shared__ u16 Bs[2][BN * 64];
  const int tid = threadIdx.x;
  const int nwg = gridDim.x;
  const int bid = blockIdx.x;
  const int swz = (bid & 7) * (nwg >> 3) + (bid >> 3);  // nwg % 8 == 0 always here
  const int by = swz / nx, bx = swz - by * nx;
  const int brow = by * 128, bcol = bx * BN;
  const int lane = tid & 63, w = tid >> 6;
  const int wr = (w / WC) * (MR * 16), wc = (w % WC) * 32;
  const int fr = lane & 15, fg = lane >> 4;
  const int swb = (fr & 7) << 4;            // read-side XOR (bytes within 128B row)
  const int ldr = lane >> 3;                // row within 8-row staging chunk
  const int lc8 = lane & 7;                 // 16B slot
  const int cs8 = (lc8 ^ ldr) * 8;          // inverse-swizzled source column (elems)

  const u16* Ab = A + (size_t)(brow + ldr) * K + cs8;
  const u16* Bb = B + (size_t)(bcol + ldr) * K + cs8;

  f32x4 acc[MR][2];
  const f32x4 z = {0.f, 0.f, 0.f, 0.f};
#pragma unroll
  for (int m = 0; m < MR; ++m) { acc[m][0] = z; acc[m][1] = z; }

  auto stage = [&](int kt, int buf) {
    const int k0 = kt << 6;
#pragma unroll
    for (int i = 0; i < 2; ++i) {
      const int c = i * 8 + w;
      __builtin_amdgcn_global_load_lds(GPTR(Ab + (size_t)c * 8 * K + k0),
                                       LPTR(&As[buf][c * 512 + lane * 8]), 16, 0, 0);
    }
#pragma unroll
    for (int i = 0; i < BN / 64; ++i) {
      const int c = i * 8 + w;
      __builtin_amdgcn_global_load_lds(GPTR(Bb + (size_t)c * 8 * K + k0),
                                       LPTR(&Bs[buf][c * 512 + lane * 8]), 16, 0, 0);
    }
  };

  stage(0, 0);
  const int nkt = K >> 6;
  for (int kt = 0; kt < nkt; ++kt) {
    const int buf = kt & 1;
    asm volatile("s_waitcnt vmcnt(0)" ::: "memory");
    __builtin_amdgcn_s_barrier();
    __builtin_amdgcn_sched_barrier(0);
    if (kt + 1 < nkt) stage(kt + 1, buf ^ 1);
    const char* Asb = (const char*)&As[buf][0];
    const char* Bsb = (const char*)&Bs[buf][0];
    __builtin_amdgcn_s_setprio(1);
#pragma unroll
    for (int ks = 0; ks < 2; ++ks) {
      bf16x8 af[MR], bfr[2];
      const int cb = (ks * 64 + fg * 16) ^ swb;
#pragma unroll
      for (int m = 0; m < MR; ++m)
        af[m] = *(const bf16x8*)(Asb + (wr + m * 16 + fr) * 128 + cb);
#pragma unroll
      for (int n = 0; n < 2; ++n)
        bfr[n] = *(const bf16x8*)(Bsb + (wc + n * 16 + fr) * 128 + cb);
#pragma unroll
      for (int m = 0; m < MR; ++m)
#pragma unroll
        for (int n = 0; n < 2; ++n)
          acc[m][n] = __builtin_amdgcn_mfma_f32_16x16x32_bf16(af[m], bfr[n], acc[m][n], 0, 0, 0);
    }
    __builtin_amdgcn_s_setprio(0);
  }

#pragma unroll
  for (int n = 0; n < 2; ++n) {
    const int col = bcol + wc + n * 16 + fr;
    const float bv = bias[col];
#pragma unroll
    for (int m = 0; m < MR; ++m) {
      const int row0 = brow + wr + m * 16 + fg * 4;
#pragma unroll
      for (int j = 0; j < 4; ++j) {
        float v = acc[m][n][j] + bv;
        const size_t idx = (size_t)(row0 + j) * N + col;
        if (EPI == 0) Cb[idx] = f2bf(gelu_f(v));
        else if (EPI == 1) Cb[idx] = f2bf(v);
        else if (EPI == 2) Cb[idx] = f2bf(bf2f(Cb[idx]) + v);
        else Cb[idx] = f2bf(fmaxf(v, 0.f));
      }
    }
  }
}

// ---------------------------------------------------------------- attention: one block per (b,h)
__global__ __launch_bounds__(256) void attn_k(const u16* __restrict__ qkv, u16* __restrict__ o) {
  constexpr int LDQ = 136;  // padded stride (bf16 elems)
  __shared__ u16 Q[36 * LDQ], Kk[36 * LDQ], V[36 * LDQ];
  __shared__ float S[36][38];
  const int tid = threadIdx.x;
  const int b = blockIdx.x >> 3, h = blockIdx.x & 7;
  const size_t base = (size_t)b * 36 * 3072 + h * 128;
  for (int i = tid; i < 36 * 16; i += 256) {
    const int r = i >> 4, c = (i & 15) << 3;
    const size_t src = base + (size_t)r * 3072 + c;
    *(uint4*)&Q[r * LDQ + c] = *(const uint4*)&qkv[src];
    *(uint4*)&Kk[r * LDQ + c] = *(const uint4*)&qkv[src + 1024];
    *(uint4*)&V[r * LDQ + c] = *(const uint4*)&qkv[src + 2048];
  }
  __syncthreads();
  for (int i = tid; i < 36 * 36; i += 256) {
    const int r = i / 36, c = i - r * 36;
    float s = 0.f;
    for (int d = 0; d < 128; ++d) s += bf2f(Q[r * LDQ + d]) * bf2f(Kk[c * LDQ + d]);
    S[r][c] = s * 0.08838834764831845f;
  }
  __syncthreads();
  if (tid < 36) {
    float mx = -1e30f;
    for (int c = 0; c < 36; ++c) mx = fmaxf(mx, S[tid][c]);
    float sum = 0.f;
    for (int c = 0; c < 36; ++c) { float e = expf(S[tid][c] - mx); S[tid][c] = e; sum += e; }
    const float inv = 1.f / sum;
    for (int c = 0; c < 36; ++c) S[tid][c] *= inv;
  }
  __syncthreads();
  for (int i = tid; i < 36 * 16; i += 256) {
    const int r = i >> 4, d0 = (i & 15) << 3;
    float s[8] = {0.f, 0.f, 0.f, 0.f, 0.f, 0.f, 0.f, 0.f};
    for (int j = 0; j < 36; ++j) {
      const float p = S[r][j];
#pragma unroll
      for (int e = 0; e < 8; ++e) s[e] += p * bf2f(V[j * LDQ + d0 + e]);
    }
    uint4 pk;
    pk.x = (u32)f2bf(s[0]) | ((u32)f2bf(s[1]) << 16);
    pk.y = (u32)f2bf(s[2]) | ((u32)f2bf(s[3]) << 16);
    pk.z = (u32)f2bf(s[4]) | ((u32)f2bf(s[5]) << 16);
    pk.w = (u32)f2bf(s[6]) | ((u32)f2bf(s[7]) << 16);
    *(uint4*)&o[(size_t)(b * 36 + r) * 1024 + h * 128 + d0] = pk;
  }
}

// ---------------------------------------------------------------- attention-map head (per token)
__global__ __launch_bounds__(256) void h0_k(const u16* __restrict__ xr,
                                            const float* __restrict__ w1t,
                                            const float* __restrict__ b1,
                                            const float* __restrict__ w2,
                                            const float* __restrict__ b2v,
                                            float* __restrict__ full) {
  __shared__ float xs[1024];
  __shared__ float hp[4][64];
  const int token = blockIdx.x, tid = threadIdx.x;
  {
    ushort4 u = ((const ushort4*)(xr + (size_t)token * 1024))[tid];
    ((float4*)xs)[tid] = make_float4(bf2f(u.x), bf2f(u.y), bf2f(u.z), bf2f(u.w));
  }
  __syncthreads();
  const int w = tid >> 6, lane = tid & 63;
  float s = 0.f;
  const int c0 = w * 256;
  for (int c = c0; c < c0 + 256; ++c) s += xs[c] * w1t[c * 64 + lane];
  hp[w][lane] = s;
  __syncthreads();
  if (tid < 64) {
    float h = hp[0][tid] + hp[1][tid] + hp[2][tid] + hp[3][tid] + b1[tid];
    h = gelu_f(h);
    float v = h * w2[tid];
#pragma unroll
    for (int off = 32; off; off >>= 1) v += __shfl_down(v, off);
    if (tid == 0) full[token] = v + b2v[0];
  }
}

__global__ void am2_k(const float* __restrict__ full, const float* __restrict__ temp,
                      float* __restrict__ out) {
  const int i = blockIdx.x * 256 + threadIdx.x;
  if (i < 128 * 36 * 35) {
    const int j = i % 35;
    const int t = i / 35;
    const int p = t % 36;
    const int b = t / 36;
    const int col = j + (j >= p ? 1 : 0);
    const float v = full[b * 36 + col] / temp[0];
    out[i] = 1.f / (1.f + expf(-v));
  }
}

// ---------------------------------------------------------------- launch
extern "C" void kernel_launch(void* const* d_in, const int* in_sizes, int n_in,
                              void* d_out, int out_size, void* d_ws, size_t ws_size,
                              hipStream_t stream) {
  const float* x     = (const float*)d_in[0];
  const float* ln0_g = (const float*)d_in[1];
  const float* ln0_b = (const float*)d_in[2];
  const float* Wred  = (const float*)d_in[3];
  const float* bred  = (const float*)d_in[4];
  const float* h0_w1 = (const float*)d_in[5];
  const float* h0_b1 = (const float*)d_in[6];
  const float* h0_w2 = (const float*)d_in[7];
  const float* h0_b2 = (const float*)d_in[8];
  const float* temp  = (const float*)d_in[9];
  const float* Wqkv  = (const float*)d_in[10];
  const float* bqkv  = (const float*)d_in[11];
  const float* Wo    = (const float*)d_in[12];
  const float* bo    = (const float*)d_in[13];
  const float* ln1_g = (const float*)d_in[14];
  const float* ln1_b = (const float*)d_in[15];
  const float* W1    = (const float*)d_in[16];
  const float* b1    = (const float*)d_in[17];
  const float* W2    = (const float*)d_in[18];
  const float* b2    = (const float*)d_in[19];
  const float* ln2_g = (const float*)d_in[20];
  const float* ln2_b = (const float*)d_in[21];
  const float* lnf_g = (const float*)d_in[22];
  const float* lnf_b = (const float*)d_in[23];

  char* ws = (char*)d_ws;
  size_t off = 0;
  auto alloc = [&](size_t bytes) -> void* {
    void* p = ws + off;
    off += (bytes + 255) & ~(size_t)255;
    return p;
  };
  u16* WredB  = (u16*)alloc((size_t)1024 * 3072 * 2);
  u16* WqkvB  = (u16*)alloc((size_t)6 * 3072 * 1024 * 2);
  u16* WoB    = (u16*)alloc((size_t)6 * 1024 * 1024 * 2);
  u16* W1B    = (u16*)alloc((size_t)6 * 2048 * 1024 * 2);
  u16* W2B    = (u16*)alloc((size_t)6 * 1024 * 2048 * 2);
  float* w1t  = (float*)alloc((size_t)1024 * 64 * 4);
  u16* yb     = (u16*)alloc((size_t)4608 * 1024 * 2);   // residual stream (bf16)
  u16* big    = (u16*)alloc((size_t)4608 * 3072 * 2);   // xn / qkv / f
  u16* nbuf   = (u16*)alloc((size_t)4608 * 1024 * 2);   // ynorm / o
  float* fullb = (float*)alloc((size_t)4608 * 4);

  auto cvt = [&](const float* src, u16* dst, size_t n) {
    int n4 = (int)(n / 4);
    cvt_k<<<(n4 + 255) / 256, 256, 0, stream>>>(src, dst, n4);
  };
  cvt(Wred, WredB, (size_t)1024 * 3072);
  cvt(Wqkv, WqkvB, (size_t)6 * 3072 * 1024);
  cvt(Wo,   WoB,   (size_t)6 * 1024 * 1024);
  cvt(W1,   W1B,   (size_t)6 * 2048 * 1024);
  cvt(W2,   W2B,   (size_t)6 * 1024 * 2048);
  w1t_k<<<64 * 1024 / 256, 256, 0, stream>>>(h0_w1, w1t);

  // dim reduce: xr = gelu(LN0(x) @ Wred^T + bred) -> yb (bf16)
  ln_k<3072, 0, 0><<<4608, 256, 0, stream>>>(x, ln0_g, ln0_b, big);
  gemm_bt<0, 64><<<16 * 36, 512, 0, stream>>>(big, WredB, bred, yb, 1024, 3072, 16);
  // attention maps head
  h0_k<<<4608, 256, 0, stream>>>(yb, w1t, h0_b1, h0_w2, h0_b2, fullb);
  am2_k<<<(128 * 36 * 35 + 255) / 256, 256, 0, stream>>>(fullb, temp,
                                                         (float*)d_out + 4608 * 1024);

  for (int l = 0; l < 6; ++l) {
    ln_k<1024, 0, 1><<<4608, 256, 0, stream>>>(yb, ln1_g + l * 1024, ln1_b + l * 1024, nbuf);
    gemm_bt<1, 128><<<24 * 36, 512, 0, stream>>>(nbuf, WqkvB + (size_t)l * 3072 * 1024,
                                                 bqkv + l * 3072, big, 3072, 1024, 24);
    attn_k<<<128 * 8, 256, 0, stream>>>(big, nbuf);
    gemm_bt<2, 64><<<16 * 36, 512, 0, stream>>>(nbuf, WoB + (size_t)l * 1024 * 1024,
                                                bo + l * 1024, yb, 1024, 1024, 16);
    ln_k<1024, 0, 1><<<4608, 256, 0, stream>>>(yb, ln2_g + l * 1024, ln2_b + l * 1024, nbuf);
    gemm_bt<3, 128><<<16 * 36, 512, 0, stream>>>(nbuf, W1B + (size_t)l * 2048 * 1024,
                                                 b1 + l * 2048, big, 2048, 1024, 16);
    gemm_bt<2, 64><<<16 * 36, 512, 0, stream>>>(big, W2B + (size_t)l * 1024 * 2048,
                                                b2 + l * 1024, yb, 1024, 2048, 16);
  }
  ln_k<1024, 1, 1><<<4608, 256, 0, stream>>>(yb, lnf_g, lnf_b, d_out);
}